// Round 19
// baseline (241.963 us; speedup 1.0000x reference)
//
#include <hip/hip_runtime.h>
#include <math.h>

using bf16   = __bf16;
using bf16x8 = __attribute__((ext_vector_type(8))) __bf16;
using bf16x4 = __attribute__((ext_vector_type(4))) __bf16;
using f32x4  = __attribute__((ext_vector_type(4))) float;
using f32x16 = __attribute__((ext_vector_type(16))) float;
using uint2v = __attribute__((ext_vector_type(2))) unsigned int;

#define MFMA_16x16x32(a, b, c) __builtin_amdgcn_mfma_f32_16x16x32_bf16((a), (b), (c), 0, 0, 0)
#define MFMA32(a, b, c) __builtin_amdgcn_mfma_f32_32x32x16_bf16((a), (b), (c), 0, 0, 0)

__device__ __forceinline__ void gll16(const void* g, void* l) {
  __builtin_amdgcn_global_load_lds((const __attribute__((address_space(1))) void*)g,
                                   (__attribute__((address_space(3))) void*)l,
                                   16, 0, 0);
}

__device__ __forceinline__ int cvtpk(float lo, float hi) {
  int r;
  asm("v_cvt_pk_bf16_f32 %0, %1, %2" : "=v"(r) : "v"(lo), "v"(hi));
  return r;
}

// gelu(x) = x * e/(e+1), e = exp2(2*log2e * 0.79788456*(x + 0.044715 x^3))
__device__ __forceinline__ float gelu_fast(float x) {
  const float u = 0.7978845608f * __builtin_fmaf(0.044715f * x, x * x, x);
  const float e = exp2f(2.885390082f * u);
  return x * e / (e + 1.f);
}

// ---------------- fused weight casts + LN1 ----------------
__global__ __launch_bounds__(256) void prep_kernel(const float* __restrict__ s0, bf16* d0,
                                                   const float* __restrict__ s1, bf16* d1,
                                                   const float* __restrict__ s2, bf16* d2,
                                                   const float* __restrict__ s3, bf16* d3,
                                                   const float* __restrict__ x,
                                                   const float* __restrict__ g,
                                                   const float* __restrict__ b,
                                                   bf16* __restrict__ lnout) {
  const int bid = blockIdx.x, t = threadIdx.x;
  if (bid < 12288) {
    int i = bid * 256 + t;  // in float4 units
    const float* s;
    bf16* d;
    if (i < 786432) { s = s0; d = d0; }
    else if (i < 1048576) { s = s1; d = d1; i -= 786432; }
    else if (i < 2097152) { s = s2; d = d2; i -= 1048576; }
    else { s = s3; d = d3; i -= 2097152; }
    float4 v = ((const float4*)s)[i];
    bf16x4 o;
    o[0] = (bf16)v.x; o[1] = (bf16)v.y; o[2] = (bf16)v.z; o[3] = (bf16)v.w;
    ((bf16x4*)d)[i] = o;
    return;
  }
  const int row = bid - 12288;
  const float4 v = ((const float4*)(x + (size_t)row * 1024))[t];
  float s1v = v.x + v.y + v.z + v.w;
  float s2v = v.x * v.x + v.y * v.y + v.z * v.z + v.w * v.w;
#pragma unroll
  for (int d = 32; d; d >>= 1) {
    s1v += __shfl_xor(s1v, d);
    s2v += __shfl_xor(s2v, d);
  }
  __shared__ float red[8];
  const int w = t >> 6;
  if ((t & 63) == 0) { red[w] = s1v; red[4 + w] = s2v; }
  __syncthreads();
  s1v = red[0] + red[1] + red[2] + red[3];
  s2v = red[4] + red[5] + red[6] + red[7];
  const float mu = s1v * (1.f / 1024.f);
  const float rstd = rsqrtf(s2v * (1.f / 1024.f) - mu * mu + 1e-5f);
  const float4 gv = ((const float4*)g)[t];
  const float4 bv = ((const float4*)b)[t];
  bf16x4 o;
  o[0] = (bf16)((v.x - mu) * rstd * gv.x + bv.x);
  o[1] = (bf16)((v.y - mu) * rstd * gv.y + bv.y);
  o[2] = (bf16)((v.z - mu) * rstd * gv.z + bv.z);
  o[3] = (bf16)((v.w - mu) * rstd * gv.w + bv.w);
  ((bf16x4*)(lnout + (size_t)row * 1024))[t] = o;
}

// ---------------- LayerNorm (D=1024), bf16 in -> bf16 out (LN2) ----------------
__global__ __launch_bounds__(256) void ln_kernel(const bf16* __restrict__ x,
                                                 const float* __restrict__ g,
                                                 const float* __restrict__ b,
                                                 bf16* __restrict__ out) {
  const int row = blockIdx.x, t = threadIdx.x;
  const bf16x4 raw = ((const bf16x4*)(x + (size_t)row * 1024))[t];
  float4 v;
  v.x = (float)raw[0]; v.y = (float)raw[1]; v.z = (float)raw[2]; v.w = (float)raw[3];
  float s1 = v.x + v.y + v.z + v.w;
  float s2 = v.x * v.x + v.y * v.y + v.z * v.z + v.w * v.w;
#pragma unroll
  for (int d = 32; d; d >>= 1) {
    s1 += __shfl_xor(s1, d);
    s2 += __shfl_xor(s2, d);
  }
  __shared__ float red[8];
  const int w = t >> 6;
  if ((t & 63) == 0) { red[w] = s1; red[4 + w] = s2; }
  __syncthreads();
  s1 = red[0] + red[1] + red[2] + red[3];
  s2 = red[4] + red[5] + red[6] + red[7];
  const float mu = s1 * (1.f / 1024.f);
  const float rstd = rsqrtf(s2 * (1.f / 1024.f) - mu * mu + 1e-5f);
  const float4 gv = ((const float4*)g)[t];
  const float4 bv = ((const float4*)b)[t];
  bf16x4 o;
  o[0] = (bf16)((v.x - mu) * rstd * gv.x + bv.x);
  o[1] = (bf16)((v.y - mu) * rstd * gv.y + bv.y);
  o[2] = (bf16)((v.z - mu) * rstd * gv.z + bv.z);
  o[3] = (bf16)((v.w - mu) * rstd * gv.w + bv.w);
  ((bf16x4*)(out + (size_t)row * 1024))[t] = o;
}

// ============ 256x256 8-phase GEMM: C = A[M,K] @ W[N,K]^T ============
// EPI 0 (QKV): +bias -> bf16; Q cols (<1024) pre-scaled by 0.125*log2e;
//              V cols (>=2048) routed transposed into vout.
// EPI 1 (FC1): +bias, gelu -> bf16.
template <int EPI>
__global__ __launch_bounds__(512, 2) void gemm256(const bf16* __restrict__ A,
                                                  const bf16* __restrict__ W,
                                                  const float* __restrict__ bias,
                                                  bf16* __restrict__ outp,
                                                  bf16* __restrict__ vout, int N, int K,
                                                  int nbx) {
  __shared__ __align__(1024) bf16 lds[65536];
  const int t = threadIdx.x, lane = t & 63, w = t >> 6;
  const int wm = w >> 2, wn = w & 3;
  const int l15 = lane & 15, lg = lane >> 4;

  const int nwg = gridDim.x, cpx = nwg >> 3, bid = blockIdx.x;
  const int swz = (bid & 7) * cpx + (bid >> 3);
  const int bx = swz % nbx, by = swz / nbx;
  const int m0 = by * 256, n0 = bx * 256;

  const bf16* src[8];
  int dst[8];
  {
    const int ss[2] = {t, t + 512};
#pragma unroll
    for (int i = 0; i < 2; i++) {
      const int d = ss[i] * 16;
      const int L = d ^ (((d >> 9) & 1) << 5);
      const int r = L >> 7, coff = (L & 127) >> 1;
#pragma unroll
      for (int hf = 0; hf < 2; hf++) {
        src[hf * 2 + i]     = A + (size_t)(m0 + hf * 128 + r) * K + coff;
        src[4 + hf * 2 + i] = W + (size_t)(n0 + hf * 128 + r) * K + coff;
        dst[hf * 2 + i]     = hf * 8192 + ss[i] * 8;
        dst[4 + hf * 2 + i] = 16384 + hf * 8192 + ss[i] * 8;
      }
    }
  }

#define STAGE256(db_)                                   \
  do {                                                  \
    _Pragma("unroll") for (int u = 0; u < 8; u++) {     \
      gll16(src[u], lds + (db_)*32768 + dst[u]);        \
      src[u] += 64;                                     \
    }                                                   \
  } while (0)

  f32x4 acc[8][4];
#pragma unroll
  for (int mi = 0; mi < 8; mi++)
#pragma unroll
    for (int ni = 0; ni < 4; ni++) acc[mi][ni] = (f32x4){0.f, 0.f, 0.f, 0.f};

  const int ntiles = K >> 6;
  STAGE256(0);
  asm volatile("s_waitcnt vmcnt(0)" ::: "memory");
  __builtin_amdgcn_s_barrier();

  for (int kt = 0; kt < ntiles; ++kt) {
    const int db = kt & 1;
    const bf16* Ab = lds + db * 32768 + wm * 8192;
    const bf16* Bb = lds + db * 32768 + 16384 + (wn >> 1) * 8192;
    bf16x8 bfr[4][2];
#pragma unroll
    for (int p = 0; p < 4; ++p) {
      bf16x8 af[2][2];
#pragma unroll
      for (int mi2 = 0; mi2 < 2; ++mi2)
#pragma unroll
        for (int ks = 0; ks < 2; ++ks) {
          const int row = (2 * p + mi2) * 16 + l15;
          const int Pb = (row * 128 + ks * 64 + lg * 16) ^ (((row >> 2) & 1) << 5);
          af[mi2][ks] = *(const bf16x8*)((const char*)Ab + Pb);
        }
      if (p == 0) {
#pragma unroll
        for (int ni = 0; ni < 4; ++ni)
#pragma unroll
          for (int ks = 0; ks < 2; ++ks) {
            const int row = (wn & 1) * 64 + ni * 16 + l15;
            const int Pb = (row * 128 + ks * 64 + lg * 16) ^ (((row >> 2) & 1) << 5);
            bfr[ni][ks] = *(const bf16x8*)((const char*)Bb + Pb);
          }
        if (kt + 1 < ntiles) STAGE256(db ^ 1);
      }
      __builtin_amdgcn_s_barrier();
      asm volatile("s_waitcnt lgkmcnt(0)" ::: "memory");
      __builtin_amdgcn_sched_barrier(0);
      __builtin_amdgcn_s_setprio(1);
#pragma unroll
      for (int ks = 0; ks < 2; ++ks)
#pragma unroll
        for (int ni = 0; ni < 4; ++ni) {
          acc[2 * p][ni] = MFMA_16x16x32(af[0][ks], bfr[ni][ks], acc[2 * p][ni]);
          acc[2 * p + 1][ni] = MFMA_16x16x32(af[1][ks], bfr[ni][ks], acc[2 * p + 1][ni]);
        }
      __builtin_amdgcn_s_setprio(0);
      if (p == 3) asm volatile("s_waitcnt vmcnt(0)" ::: "memory");
      __builtin_amdgcn_s_barrier();
    }
  }
#undef STAGE256

  const float csq = 0.18033688011112042f;  // 0.125 * log2(e), folded into Q
#pragma unroll
  for (int mi = 0; mi < 8; ++mi) {
    const int row0 = m0 + wm * 128 + mi * 16 + lg * 4;
#pragma unroll
    for (int ni = 0; ni < 4; ++ni) {
      const int col = n0 + wn * 64 + ni * 16 + l15;
      const float bc = bias[col];
      if (EPI == 0 && col >= 2048) {
        bf16x4 ov;
#pragma unroll
        for (int r = 0; r < 4; ++r) ov[r] = (bf16)(acc[mi][ni][r] + bc);
        const int bb = row0 >> 11, s = row0 & 2047, dc = col - 2048;
        *(bf16x4*)(vout + ((size_t)(bb * 16 + (dc >> 6)) * 64 + (dc & 63)) * 2048 + s) = ov;
      } else {
        float sc = 1.f;
        if (EPI == 0 && col < 1024) sc = csq;
#pragma unroll
        for (int r = 0; r < 4; ++r) {
          float v = acc[mi][ni][r] + bc;
          if (EPI == 1) v = gelu_fast(v);
          outp[(size_t)(row0 + r) * N + col] = (bf16)(v * sc);
        }
      }
    }
  }
}

// ============ 64x128 GEMM, BK=64: +bias +resid ============
// MODE 0: resid fp32, out bf16 | MODE 1: resid bf16, out fp32
template <int MODE>
__global__ __launch_bounds__(256, 3) void gemm64(const bf16* __restrict__ A,
                                                 const bf16* __restrict__ W,
                                                 const float* __restrict__ bias,
                                                 const void* __restrict__ residv,
                                                 void* __restrict__ outv, int N, int K,
                                                 int nbx) {
  __shared__ __align__(1024) bf16 lds[24576];
  const int t = threadIdx.x, lane = t & 63, w = t >> 6;
  const int wm = w >> 1, wn = w & 1;
  const int l15 = lane & 15, lg = lane >> 4;

  const int nwg = gridDim.x, cpx = nwg >> 3, bid = blockIdx.x;
  const int swz = (bid & 7) * cpx + (bid >> 3);
  const int bx = swz % nbx, by = swz / nbx;
  const int m0 = by * 64, n0 = bx * 128;

  const bf16* src[6];
  int dst[6];
#pragma unroll
  for (int u = 0; u < 2; ++u) {
    const int off = u * 4096 + t * 16;
    const int row = off >> 7, slot = (off >> 4) & 7;
    const int col = (slot ^ (row & 7)) * 8;
    src[u] = A + (size_t)(m0 + row) * K + col;
    dst[u] = off >> 1;
  }
#pragma unroll
  for (int u = 0; u < 4; ++u) {
    const int off = u * 4096 + t * 16;
    const int row = off >> 7, slot = (off >> 4) & 7;
    const int col = (slot ^ (row & 7)) * 8;
    src[2 + u] = W + (size_t)(n0 + row) * K + col;
    dst[2 + u] = 4096 + (off >> 1);
  }

#define STAGE64(db_)                                    \
  do {                                                  \
    _Pragma("unroll") for (int u = 0; u < 6; u++) {     \
      gll16(src[u], lds + (db_)*12288 + dst[u]);        \
      src[u] += 64;                                     \
    }                                                   \
  } while (0)

  f32x4 acc[2][4];
#pragma unroll
  for (int mi = 0; mi < 2; mi++)
#pragma unroll
    for (int ni = 0; ni < 4; ni++) acc[mi][ni] = (f32x4){0.f, 0.f, 0.f, 0.f};

  const int ntiles = K >> 6;
  STAGE64(0);
  asm volatile("s_waitcnt vmcnt(0)" ::: "memory");
  __builtin_amdgcn_s_barrier();

  for (int kt = 0; kt < ntiles; ++kt) {
    const int db = kt & 1;
    const char* Ab = (const char*)(lds + db * 12288);
    const char* Bb = (const char*)(lds + db * 12288 + 4096);
#pragma unroll
    for (int p = 0; p < 2; ++p) {
      bf16x8 af[2], bfr[4];
#pragma unroll
      for (int mi = 0; mi < 2; ++mi) {
        const int row = wm * 32 + mi * 16 + l15;
        af[mi] = *(const bf16x8*)(Ab + row * 128 + (((p * 4 + lg) ^ (row & 7)) << 4));
      }
#pragma unroll
      for (int ni = 0; ni < 4; ++ni) {
        const int row = wn * 64 + ni * 16 + l15;
        bfr[ni] = *(const bf16x8*)(Bb + row * 128 + (((p * 4 + lg) ^ (row & 7)) << 4));
      }
      if (p == 0 && kt + 1 < ntiles) STAGE64(db ^ 1);
      __builtin_amdgcn_s_barrier();
      asm volatile("s_waitcnt lgkmcnt(0)" ::: "memory");
      __builtin_amdgcn_sched_barrier(0);
      __builtin_amdgcn_s_setprio(1);
#pragma unroll
      for (int mi = 0; mi < 2; ++mi)
#pragma unroll
        for (int ni = 0; ni < 4; ++ni)
          acc[mi][ni] = MFMA_16x16x32(af[mi], bfr[ni], acc[mi][ni]);
      __builtin_amdgcn_s_setprio(0);
      if (p == 1) asm volatile("s_waitcnt vmcnt(0)" ::: "memory");
      __builtin_amdgcn_s_barrier();
    }
  }
#undef STAGE64

#pragma unroll
  for (int mi = 0; mi < 2; ++mi) {
    const int row0 = m0 + wm * 32 + mi * 16 + lg * 4;
#pragma unroll
    for (int ni = 0; ni < 4; ++ni) {
      const int col = n0 + wn * 64 + ni * 16 + l15;
      const float bc = bias[col];
#pragma unroll
      for (int r = 0; r < 4; ++r) {
        const size_t idx = (size_t)(row0 + r) * N + col;
        float v = acc[mi][ni][r] + bc;
        if (MODE == 0) {
          v += ((const float*)residv)[idx];
          ((bf16*)outv)[idx] = (bf16)v;
        } else {
          v += (float)((const bf16*)residv)[idx];
          ((float*)outv)[idx] = v;
        }
      }
    }
  }
}

// ========== Split-KV flash attention (causal), swapped-QK, static-max softmax ==========
// Static-max (m=0) makes partials EXACTLY additive: O = O_A + O_B, ls = lsA + lsB.
// Grid (32,32) = 1024 blocks; (qb,sx) from stagger remap; each block does qb+1 kv-tiles
// (half the causal prefix) -> trip counts 1..16 (was 2..32), 2x blocks for TLP/backfill.
// Writes f32 partial O [sx][4096][1024] + partial lsum [sx][32][2048].
__global__ __launch_bounds__(256) void attn_kernel(const bf16* __restrict__ qkv,
                                                   const bf16* __restrict__ vt,
                                                   float* __restrict__ pO,
                                                   float* __restrict__ pls) {
  __shared__ bf16 Ks[3][4096];
  __shared__ bf16 Vs[3][4096];
  const int t = threadIdx.x, lane = t & 63, w = t >> 6;
  const int l31 = lane & 31, lh = lane >> 5;
  const int bx = blockIdx.x, by = blockIdx.y;
  const int b = by >> 4, h = by & 15;
  const int gg = (bx + by) & 31;   // stagger (qb,sx) across dispatch order
  const int qb = gg >> 1, sx = gg & 1;
  const int qw = qb * 128 + w * 32;
  const int qq = qw + l31;
  const int nt = qb + 1;           // local trip count (half the prefix)
  const int t0 = sx * nt;          // first kv tile of this half

  bf16x8 qf[4];
  {
    const bf16* qp = qkv + (size_t)(b * 2048 + qq) * 3072 + h * 64 + lh * 8;
#pragma unroll
    for (int c = 0; c < 4; ++c) qf[c] = *(const bf16x8*)(qp + c * 16);
  }

  const int r0 = t >> 3, c16 = t & 7;
  const int swsl = 8 * (c16 ^ (r0 & 7));
  const bf16* kp0 = qkv + (size_t)(b * 2048 + t0 * 64 + r0) * 3072 + 1024 + h * 64 + swsl;
  const bf16* kp1 = kp0 + (size_t)32 * 3072;
  const bf16* vp0 = vt + ((size_t)by * 64 + r0) * 2048 + t0 * 64 + swsl;
  const bf16* vp1 = vp0 + (size_t)32 * 2048;

#define ASTAGE(buf)                          \
  do {                                       \
    gll16(kp0, &Ks[buf][t * 8]);             \
    gll16(kp1, &Ks[buf][2048 + t * 8]);      \
    gll16(vp0, &Vs[buf][t * 8]);             \
    gll16(vp1, &Vs[buf][2048 + t * 8]);      \
    kp0 += (size_t)64 * 3072;                \
    kp1 += (size_t)64 * 3072;                \
    vp0 += 64;                               \
    vp1 += 64;                               \
  } while (0)

  const f32x16 z16 = {0.f, 0.f, 0.f, 0.f, 0.f, 0.f, 0.f, 0.f,
                      0.f, 0.f, 0.f, 0.f, 0.f, 0.f, 0.f, 0.f};
  f32x16 o0a = z16, o0b = z16, o1a = z16, o1b = z16;
  float lsum = 0.f;

  ASTAGE(0);
  ASTAGE(1);  // tile t0+1 <= 17 < 32: always within the sequence
  int b0 = 0, b1 = 1, b2 = 2;
  for (int tt = 0; tt < nt; ++tt) {
    const int kv0 = (t0 + tt) * 64;
    if (tt < nt - 1) asm volatile("s_waitcnt vmcnt(4)" ::: "memory");
    else             asm volatile("s_waitcnt vmcnt(0)" ::: "memory");
    __builtin_amdgcn_s_barrier();
    if (tt + 2 < nt) ASTAGE(b2);
    if (kv0 <= qw + 31) {
      const bf16* kbp = Ks[b0];
      const bf16* vbp = Vs[b0];
      const bool up = (kv0 + 32) <= (qw + 31);
      f32x16 s0v = z16, s1v = z16;
      __builtin_amdgcn_s_setprio(1);
#pragma unroll
      for (int c = 0; c < 4; ++c) {
        const int slot = ((c * 2 + lh) ^ (l31 & 7)) * 16;
        const bf16x8 a0 = *(const bf16x8*)((const char*)kbp + l31 * 128 + slot);
        s0v = MFMA32(a0, qf[c], s0v);
      }
      if (up) {
#pragma unroll
        for (int c = 0; c < 4; ++c) {
          const int slot = ((c * 2 + lh) ^ (l31 & 7)) * 16;
          const bf16x8 a1 = *(const bf16x8*)((const char*)kbp + (32 + l31) * 128 + slot);
          s1v = MFMA32(a1, qf[c], s1v);
        }
      }
      __builtin_amdgcn_s_setprio(0);
      if (kv0 + 64 > qw) {
#pragma unroll
        for (int j = 0; j < 16; ++j) {
          const int kr = kv0 + (j & 3) + 8 * (j >> 2) + 4 * lh;
          if (kr > qq) s0v[j] = -1e30f;
          if (kr + 32 > qq) s1v[j] = -1e30f;
        }
      }
#pragma unroll
      for (int j = 0; j < 16; ++j) {
        s0v[j] = exp2f(s0v[j]);
        lsum += s0v[j];
      }
      if (up) {
#pragma unroll
        for (int j = 0; j < 16; ++j) {
          s1v[j] = exp2f(s1v[j]);
          lsum += s1v[j];
        }
      }
      unsigned int w0[8];
#pragma unroll
      for (int j = 0; j < 8; ++j) w0[j] = (unsigned int)cvtpk(s0v[2 * j], s0v[2 * j + 1]);
#define PVHALF2(WW, KB, OA, OB)                                                      \
  do {                                                                               \
    const uint2v e0 = __builtin_amdgcn_permlane32_swap(WW[0], WW[2], false, false);  \
    const uint2v e1 = __builtin_amdgcn_permlane32_swap(WW[1], WW[3], false, false);  \
    const uint2v e2 = __builtin_amdgcn_permlane32_swap(WW[4], WW[6], false, false);  \
    const uint2v e3 = __builtin_amdgcn_permlane32_swap(WW[5], WW[7], false, false);  \
    union { unsigned int i[4]; bf16x8 v; } pA, pB;                                   \
    pA.i[0] = e0[0]; pA.i[1] = e1[0]; pA.i[2] = e0[1]; pA.i[3] = e1[1];              \
    pB.i[0] = e2[0]; pB.i[1] = e3[0]; pB.i[2] = e2[1]; pB.i[3] = e3[1];              \
    const int sA = (((KB)*4 + lh) ^ (l31 & 7)) * 16;                                 \
    const int sB = (((KB)*4 + 2 + lh) ^ (l31 & 7)) * 16;                             \
    const bf16x8 vA0 = *(const bf16x8*)((const char*)vbp + l31 * 128 + sA);          \
    const bf16x8 vA1 = *(const bf16x8*)((const char*)vbp + (32 + l31) * 128 + sA);   \
    const bf16x8 vB0 = *(const bf16x8*)((const char*)vbp + l31 * 128 + sB);          \
    const bf16x8 vB1 = *(const bf16x8*)((const char*)vbp + (32 + l31) * 128 + sB);   \
    OA = MFMA32(vA0, pA.v, OA);                                                      \
    OB = MFMA32(vA1, pA.v, OB);                                                      \
    OA = MFMA32(vB0, pB.v, OA);                                                      \
    OB = MFMA32(vB1, pB.v, OB);                                                      \
  } while (0)
      __builtin_amdgcn_s_setprio(1);
      PVHALF2(w0, 0, o0a, o1a);
      __builtin_amdgcn_s_setprio(0);
      if (up) {
        unsigned int w1[8];
#pragma unroll
        for (int j = 0; j < 8; ++j) w1[j] = (unsigned int)cvtpk(s1v[2 * j], s1v[2 * j + 1]);
        __builtin_amdgcn_s_setprio(1);
        PVHALF2(w1, 1, o0b, o1b);
        __builtin_amdgcn_s_setprio(0);
      }
#undef PVHALF2
    }
    const int tmp = b0; b0 = b1; b1 = b2; b2 = tmp;
  }
#undef ASTAGE

  lsum += __shfl_xor(lsum, 32);  // partner holds the other key-half of the same tiles
  if (lh == 0) pls[sx * 65536 + by * 2048 + qq] = lsum;
  const f32x16 oacc0 = o0a + o0b, oacc1 = o1a + o1b;
  float* pop = pO + (size_t)sx * 4194304 + (size_t)(b * 2048 + qq) * 1024 + h * 64;
#pragma unroll
  for (int gR = 0; gR < 4; ++gR) {
    f32x4 q0, q1;
#pragma unroll
    for (int r = 0; r < 4; ++r) {
      q0[r] = oacc0[4 * gR + r];
      q1[r] = oacc1[4 * gR + r];
    }
    *(f32x4*)(pop + 8 * gR + 4 * lh) = q0;
    *(f32x4*)(pop + 32 + 8 * gR + 4 * lh) = q1;
  }
}

// ---------------- combine: O = (O_A + O_B) / (lsA + lsB) -> bf16 ----------------
__global__ __launch_bounds__(256) void attn_combine(const float* __restrict__ pO,
                                                    const float* __restrict__ pls,
                                                    bf16* __restrict__ atto) {
  const int row = blockIdx.x;      // 0..4095
  const int t = threadIdx.x;
  const int col = t * 4;           // 0..1023
  const int b = row >> 11, s = row & 2047, h = col >> 6;
  const int lsidx = (b * 16 + h) * 2048 + s;
  const float rinv = 1.f / (pls[lsidx] + pls[65536 + lsidx]);
  const size_t io = (size_t)row * 1024 + col;
  const f32x4 a = *(const f32x4*)(pO + io);
  const f32x4 c = *(const f32x4*)(pO + 4194304 + io);
  bf16x4 o;
#pragma unroll
  for (int r = 0; r < 4; ++r) o[r] = (bf16)((a[r] + c[r]) * rinv);
  *(bf16x4*)(atto + io) = o;
}

// ---------------- launch ----------------
extern "C" void kernel_launch(void* const* d_in, const int* in_sizes, int n_in,
                              void* d_out, int out_size, void* d_ws, size_t ws_size,
                              hipStream_t stream) {
  (void)in_sizes; (void)n_in; (void)out_size; (void)ws_size;
  const float* hidden = (const float*)d_in[0];
  const float* qkv_w  = (const float*)d_in[1];
  const float* qkv_b  = (const float*)d_in[2];
  const float* out_w  = (const float*)d_in[3];
  const float* out_b  = (const float*)d_in[4];
  const float* fc1_w  = (const float*)d_in[5];
  const float* fc1_b  = (const float*)d_in[6];
  const float* fc2_w  = (const float*)d_in[7];
  const float* fc2_b  = (const float*)d_in[8];
  const float* ln1_g  = (const float*)d_in[9];
  const float* ln1_b  = (const float*)d_in[10];
  const float* ln2_g  = (const float*)d_in[11];
  const float* ln2_b  = (const float*)d_in[12];
  float* outp = (float*)d_out;

  char* ws = (char*)d_ws;
  bf16*  ln1o  = (bf16*)(ws);                         //  0-8
  bf16*  qkvb  = (bf16*)(ws + ((size_t)8 << 20));     //  8-32
  bf16*  vtb   = (bf16*)(ws + ((size_t)32 << 20));    // 32-40
  bf16*  atto  = (bf16*)(ws + ((size_t)40 << 20));    // 40-48
  bf16*  res1b = (bf16*)(ws + ((size_t)48 << 20));    // 48-56 (after partials dead)
  bf16*  ln2o  = (bf16*)(ws + ((size_t)64 << 20));    // 64-72 (after partials dead)
  bf16*  ff1   = (bf16*)(ws + ((size_t)72 << 20));    // 72-104 (after partials dead)
  float* pO    = (float*)(ws + ((size_t)48 << 20));   // 48-80: f32 partials (transient)
  float* plsb  = (float*)(ws + ((size_t)80 << 20));   // 80-80.5: partial lsums (transient)
  bf16*  wqkv  = (bf16*)(ws + ((size_t)104 << 20));
  bf16*  wout  = (bf16*)(ws + ((size_t)110 << 20));
  bf16*  wfc1  = (bf16*)(ws + ((size_t)112 << 20));
  bf16*  wfc2  = (bf16*)(ws + ((size_t)120 << 20));

  prep_kernel<<<16384, 256, 0, stream>>>(qkv_w, wqkv, out_w, wout, fc1_w, wfc1, fc2_w, wfc2,
                                         hidden, ln1_g, ln1_b, ln1o);
  gemm256<0><<<192, 512, 0, stream>>>(ln1o, wqkv, qkv_b, qkvb, vtb, 3072, 1024, 12);
  // split-KV attention -> f32 partials, then exact combine
  attn_kernel<<<dim3(32, 32), 256, 0, stream>>>(qkvb, vtb, pO, plsb);
  attn_combine<<<4096, 256, 0, stream>>>(pO, plsb, atto);
  gemm64<0><<<512, 256, 0, stream>>>(atto, wout, out_b, hidden, res1b, 1024, 1024, 8);
  ln_kernel<<<4096, 256, 0, stream>>>(res1b, ln2_g, ln2_b, ln2o);
  gemm256<1><<<256, 512, 0, stream>>>(ln2o, wfc1, fc1_b, ff1, nullptr, 4096, 1024, 16);
  gemm64<1><<<512, 256, 0, stream>>>(ff1, wfc2, fc2_b, res1b, outp, 1024, 4096, 8);
}

// Round 20
// 228.989 us; speedup vs baseline: 1.0567x; 1.0567x over previous
//
#include <hip/hip_runtime.h>
#include <math.h>

using bf16   = __bf16;
using bf16x8 = __attribute__((ext_vector_type(8))) __bf16;
using bf16x4 = __attribute__((ext_vector_type(4))) __bf16;
using f32x4  = __attribute__((ext_vector_type(4))) float;
using f32x16 = __attribute__((ext_vector_type(16))) float;
using uint2v = __attribute__((ext_vector_type(2))) unsigned int;

#define MFMA_16x16x32(a, b, c) __builtin_amdgcn_mfma_f32_16x16x32_bf16((a), (b), (c), 0, 0, 0)
#define MFMA32(a, b, c) __builtin_amdgcn_mfma_f32_32x32x16_bf16((a), (b), (c), 0, 0, 0)

__device__ __forceinline__ void gll16(const void* g, void* l) {
  __builtin_amdgcn_global_load_lds((const __attribute__((address_space(1))) void*)g,
                                   (__attribute__((address_space(3))) void*)l,
                                   16, 0, 0);
}

__device__ __forceinline__ int cvtpk(float lo, float hi) {
  int r;
  asm("v_cvt_pk_bf16_f32 %0, %1, %2" : "=v"(r) : "v"(lo), "v"(hi));
  return r;
}

// gelu(x) = x * e/(e+1), e = exp2(2*log2e * 0.79788456*(x + 0.044715 x^3))
__device__ __forceinline__ float gelu_fast(float x) {
  const float u = 0.7978845608f * __builtin_fmaf(0.044715f * x, x * x, x);
  const float e = exp2f(2.885390082f * u);
  return x * e / (e + 1.f);
}

// ---------------- fused weight casts + LN1 ----------------
__global__ __launch_bounds__(256) void prep_kernel(const float* __restrict__ s0, bf16* d0,
                                                   const float* __restrict__ s1, bf16* d1,
                                                   const float* __restrict__ s2, bf16* d2,
                                                   const float* __restrict__ s3, bf16* d3,
                                                   const float* __restrict__ x,
                                                   const float* __restrict__ g,
                                                   const float* __restrict__ b,
                                                   bf16* __restrict__ lnout) {
  const int bid = blockIdx.x, t = threadIdx.x;
  if (bid < 12288) {
    int i = bid * 256 + t;  // in float4 units
    const float* s;
    bf16* d;
    if (i < 786432) { s = s0; d = d0; }
    else if (i < 1048576) { s = s1; d = d1; i -= 786432; }
    else if (i < 2097152) { s = s2; d = d2; i -= 1048576; }
    else { s = s3; d = d3; i -= 2097152; }
    float4 v = ((const float4*)s)[i];
    bf16x4 o;
    o[0] = (bf16)v.x; o[1] = (bf16)v.y; o[2] = (bf16)v.z; o[3] = (bf16)v.w;
    ((bf16x4*)d)[i] = o;
    return;
  }
  const int row = bid - 12288;
  const float4 v = ((const float4*)(x + (size_t)row * 1024))[t];
  float s1v = v.x + v.y + v.z + v.w;
  float s2v = v.x * v.x + v.y * v.y + v.z * v.z + v.w * v.w;
#pragma unroll
  for (int d = 32; d; d >>= 1) {
    s1v += __shfl_xor(s1v, d);
    s2v += __shfl_xor(s2v, d);
  }
  __shared__ float red[8];
  const int w = t >> 6;
  if ((t & 63) == 0) { red[w] = s1v; red[4 + w] = s2v; }
  __syncthreads();
  s1v = red[0] + red[1] + red[2] + red[3];
  s2v = red[4] + red[5] + red[6] + red[7];
  const float mu = s1v * (1.f / 1024.f);
  const float rstd = rsqrtf(s2v * (1.f / 1024.f) - mu * mu + 1e-5f);
  const float4 gv = ((const float4*)g)[t];
  const float4 bv = ((const float4*)b)[t];
  bf16x4 o;
  o[0] = (bf16)((v.x - mu) * rstd * gv.x + bv.x);
  o[1] = (bf16)((v.y - mu) * rstd * gv.y + bv.y);
  o[2] = (bf16)((v.z - mu) * rstd * gv.z + bv.z);
  o[3] = (bf16)((v.w - mu) * rstd * gv.w + bv.w);
  ((bf16x4*)(lnout + (size_t)row * 1024))[t] = o;
}

// ---------------- LayerNorm (D=1024), bf16 in -> bf16 out (LN2) ----------------
__global__ __launch_bounds__(256) void ln_kernel(const bf16* __restrict__ x,
                                                 const float* __restrict__ g,
                                                 const float* __restrict__ b,
                                                 bf16* __restrict__ out) {
  const int row = blockIdx.x, t = threadIdx.x;
  const bf16x4 raw = ((const bf16x4*)(x + (size_t)row * 1024))[t];
  float4 v;
  v.x = (float)raw[0]; v.y = (float)raw[1]; v.z = (float)raw[2]; v.w = (float)raw[3];
  float s1 = v.x + v.y + v.z + v.w;
  float s2 = v.x * v.x + v.y * v.y + v.z * v.z + v.w * v.w;
#pragma unroll
  for (int d = 32; d; d >>= 1) {
    s1 += __shfl_xor(s1, d);
    s2 += __shfl_xor(s2, d);
  }
  __shared__ float red[8];
  const int w = t >> 6;
  if ((t & 63) == 0) { red[w] = s1; red[4 + w] = s2; }
  __syncthreads();
  s1 = red[0] + red[1] + red[2] + red[3];
  s2 = red[4] + red[5] + red[6] + red[7];
  const float mu = s1 * (1.f / 1024.f);
  const float rstd = rsqrtf(s2 * (1.f / 1024.f) - mu * mu + 1e-5f);
  const float4 gv = ((const float4*)g)[t];
  const float4 bv = ((const float4*)b)[t];
  bf16x4 o;
  o[0] = (bf16)((v.x - mu) * rstd * gv.x + bv.x);
  o[1] = (bf16)((v.y - mu) * rstd * gv.y + bv.y);
  o[2] = (bf16)((v.z - mu) * rstd * gv.z + bv.z);
  o[3] = (bf16)((v.w - mu) * rstd * gv.w + bv.w);
  ((bf16x4*)(out + (size_t)row * 1024))[t] = o;
}

// ============ 256x256 8-phase GEMM: C = A[M,K] @ W[N,K]^T ============
// EPI 0 (QKV): +bias -> bf16; Q cols (<1024) pre-scaled by 0.125*log2e;
//              V cols (>=2048) routed transposed into vout.
// EPI 1 (FC1): +bias, gelu -> bf16.
template <int EPI>
__global__ __launch_bounds__(512, 2) void gemm256(const bf16* __restrict__ A,
                                                  const bf16* __restrict__ W,
                                                  const float* __restrict__ bias,
                                                  bf16* __restrict__ outp,
                                                  bf16* __restrict__ vout, int N, int K,
                                                  int nbx) {
  __shared__ __align__(1024) bf16 lds[65536];
  const int t = threadIdx.x, lane = t & 63, w = t >> 6;
  const int wm = w >> 2, wn = w & 3;
  const int l15 = lane & 15, lg = lane >> 4;

  const int nwg = gridDim.x, cpx = nwg >> 3, bid = blockIdx.x;
  const int swz = (bid & 7) * cpx + (bid >> 3);
  const int bx = swz % nbx, by = swz / nbx;
  const int m0 = by * 256, n0 = bx * 256;

  const bf16* src[8];
  int dst[8];
  {
    const int ss[2] = {t, t + 512};
#pragma unroll
    for (int i = 0; i < 2; i++) {
      const int d = ss[i] * 16;
      const int L = d ^ (((d >> 9) & 1) << 5);
      const int r = L >> 7, coff = (L & 127) >> 1;
#pragma unroll
      for (int hf = 0; hf < 2; hf++) {
        src[hf * 2 + i]     = A + (size_t)(m0 + hf * 128 + r) * K + coff;
        src[4 + hf * 2 + i] = W + (size_t)(n0 + hf * 128 + r) * K + coff;
        dst[hf * 2 + i]     = hf * 8192 + ss[i] * 8;
        dst[4 + hf * 2 + i] = 16384 + hf * 8192 + ss[i] * 8;
      }
    }
  }

#define STAGE256(db_)                                   \
  do {                                                  \
    _Pragma("unroll") for (int u = 0; u < 8; u++) {     \
      gll16(src[u], lds + (db_)*32768 + dst[u]);        \
      src[u] += 64;                                     \
    }                                                   \
  } while (0)

  f32x4 acc[8][4];
#pragma unroll
  for (int mi = 0; mi < 8; mi++)
#pragma unroll
    for (int ni = 0; ni < 4; ni++) acc[mi][ni] = (f32x4){0.f, 0.f, 0.f, 0.f};

  const int ntiles = K >> 6;
  STAGE256(0);
  asm volatile("s_waitcnt vmcnt(0)" ::: "memory");
  __builtin_amdgcn_s_barrier();

  for (int kt = 0; kt < ntiles; ++kt) {
    const int db = kt & 1;
    const bf16* Ab = lds + db * 32768 + wm * 8192;
    const bf16* Bb = lds + db * 32768 + 16384 + (wn >> 1) * 8192;
    bf16x8 bfr[4][2];
#pragma unroll
    for (int p = 0; p < 4; ++p) {
      bf16x8 af[2][2];
#pragma unroll
      for (int mi2 = 0; mi2 < 2; ++mi2)
#pragma unroll
        for (int ks = 0; ks < 2; ++ks) {
          const int row = (2 * p + mi2) * 16 + l15;
          const int Pb = (row * 128 + ks * 64 + lg * 16) ^ (((row >> 2) & 1) << 5);
          af[mi2][ks] = *(const bf16x8*)((const char*)Ab + Pb);
        }
      if (p == 0) {
#pragma unroll
        for (int ni = 0; ni < 4; ++ni)
#pragma unroll
          for (int ks = 0; ks < 2; ++ks) {
            const int row = (wn & 1) * 64 + ni * 16 + l15;
            const int Pb = (row * 128 + ks * 64 + lg * 16) ^ (((row >> 2) & 1) << 5);
            bfr[ni][ks] = *(const bf16x8*)((const char*)Bb + Pb);
          }
        if (kt + 1 < ntiles) STAGE256(db ^ 1);
      }
      __builtin_amdgcn_s_barrier();
      asm volatile("s_waitcnt lgkmcnt(0)" ::: "memory");
      __builtin_amdgcn_sched_barrier(0);
      __builtin_amdgcn_s_setprio(1);
#pragma unroll
      for (int ks = 0; ks < 2; ++ks)
#pragma unroll
        for (int ni = 0; ni < 4; ++ni) {
          acc[2 * p][ni] = MFMA_16x16x32(af[0][ks], bfr[ni][ks], acc[2 * p][ni]);
          acc[2 * p + 1][ni] = MFMA_16x16x32(af[1][ks], bfr[ni][ks], acc[2 * p + 1][ni]);
        }
      __builtin_amdgcn_s_setprio(0);
      if (p == 3) asm volatile("s_waitcnt vmcnt(0)" ::: "memory");
      __builtin_amdgcn_s_barrier();
    }
  }
#undef STAGE256

  const float csq = 0.18033688011112042f;  // 0.125 * log2(e), folded into Q
#pragma unroll
  for (int mi = 0; mi < 8; ++mi) {
    const int row0 = m0 + wm * 128 + mi * 16 + lg * 4;
#pragma unroll
    for (int ni = 0; ni < 4; ++ni) {
      const int col = n0 + wn * 64 + ni * 16 + l15;
      const float bc = bias[col];
      if (EPI == 0 && col >= 2048) {
        bf16x4 ov;
#pragma unroll
        for (int r = 0; r < 4; ++r) ov[r] = (bf16)(acc[mi][ni][r] + bc);
        const int bb = row0 >> 11, s = row0 & 2047, dc = col - 2048;
        *(bf16x4*)(vout + ((size_t)(bb * 16 + (dc >> 6)) * 64 + (dc & 63)) * 2048 + s) = ov;
      } else {
        float sc = 1.f;
        if (EPI == 0 && col < 1024) sc = csq;
#pragma unroll
        for (int r = 0; r < 4; ++r) {
          float v = acc[mi][ni][r] + bc;
          if (EPI == 1) v = gelu_fast(v);
          outp[(size_t)(row0 + r) * N + col] = (bf16)(v * sc);
        }
      }
    }
  }
}

// ============ 64x128 GEMM, BK=64: +bias +resid ============
// MODE 0: resid fp32, out bf16 | MODE 1: resid bf16, out fp32
template <int MODE>
__global__ __launch_bounds__(256, 3) void gemm64(const bf16* __restrict__ A,
                                                 const bf16* __restrict__ W,
                                                 const float* __restrict__ bias,
                                                 const void* __restrict__ residv,
                                                 void* __restrict__ outv, int N, int K,
                                                 int nbx) {
  __shared__ __align__(1024) bf16 lds[24576];
  const int t = threadIdx.x, lane = t & 63, w = t >> 6;
  const int wm = w >> 1, wn = w & 1;
  const int l15 = lane & 15, lg = lane >> 4;

  const int nwg = gridDim.x, cpx = nwg >> 3, bid = blockIdx.x;
  const int swz = (bid & 7) * cpx + (bid >> 3);
  const int bx = swz % nbx, by = swz / nbx;
  const int m0 = by * 64, n0 = bx * 128;

  const bf16* src[6];
  int dst[6];
#pragma unroll
  for (int u = 0; u < 2; ++u) {
    const int off = u * 4096 + t * 16;
    const int row = off >> 7, slot = (off >> 4) & 7;
    const int col = (slot ^ (row & 7)) * 8;
    src[u] = A + (size_t)(m0 + row) * K + col;
    dst[u] = off >> 1;
  }
#pragma unroll
  for (int u = 0; u < 4; ++u) {
    const int off = u * 4096 + t * 16;
    const int row = off >> 7, slot = (off >> 4) & 7;
    const int col = (slot ^ (row & 7)) * 8;
    src[2 + u] = W + (size_t)(n0 + row) * K + col;
    dst[2 + u] = 4096 + (off >> 1);
  }

#define STAGE64(db_)                                    \
  do {                                                  \
    _Pragma("unroll") for (int u = 0; u < 6; u++) {     \
      gll16(src[u], lds + (db_)*12288 + dst[u]);        \
      src[u] += 64;                                     \
    }                                                   \
  } while (0)

  f32x4 acc[2][4];
#pragma unroll
  for (int mi = 0; mi < 2; mi++)
#pragma unroll
    for (int ni = 0; ni < 4; ni++) acc[mi][ni] = (f32x4){0.f, 0.f, 0.f, 0.f};

  const int ntiles = K >> 6;
  STAGE64(0);
  asm volatile("s_waitcnt vmcnt(0)" ::: "memory");
  __builtin_amdgcn_s_barrier();

  for (int kt = 0; kt < ntiles; ++kt) {
    const int db = kt & 1;
    const char* Ab = (const char*)(lds + db * 12288);
    const char* Bb = (const char*)(lds + db * 12288 + 4096);
#pragma unroll
    for (int p = 0; p < 2; ++p) {
      bf16x8 af[2], bfr[4];
#pragma unroll
      for (int mi = 0; mi < 2; ++mi) {
        const int row = wm * 32 + mi * 16 + l15;
        af[mi] = *(const bf16x8*)(Ab + row * 128 + (((p * 4 + lg) ^ (row & 7)) << 4));
      }
#pragma unroll
      for (int ni = 0; ni < 4; ++ni) {
        const int row = wn * 64 + ni * 16 + l15;
        bfr[ni] = *(const bf16x8*)(Bb + row * 128 + (((p * 4 + lg) ^ (row & 7)) << 4));
      }
      if (p == 0 && kt + 1 < ntiles) STAGE64(db ^ 1);
      __builtin_amdgcn_s_barrier();
      asm volatile("s_waitcnt lgkmcnt(0)" ::: "memory");
      __builtin_amdgcn_sched_barrier(0);
      __builtin_amdgcn_s_setprio(1);
#pragma unroll
      for (int mi = 0; mi < 2; ++mi)
#pragma unroll
        for (int ni = 0; ni < 4; ++ni)
          acc[mi][ni] = MFMA_16x16x32(af[mi], bfr[ni], acc[mi][ni]);
      __builtin_amdgcn_s_setprio(0);
      if (p == 1) asm volatile("s_waitcnt vmcnt(0)" ::: "memory");
      __builtin_amdgcn_s_barrier();
    }
  }
#undef STAGE64

#pragma unroll
  for (int mi = 0; mi < 2; ++mi) {
    const int row0 = m0 + wm * 32 + mi * 16 + lg * 4;
#pragma unroll
    for (int ni = 0; ni < 4; ++ni) {
      const int col = n0 + wn * 64 + ni * 16 + l15;
      const float bc = bias[col];
#pragma unroll
      for (int r = 0; r < 4; ++r) {
        const size_t idx = (size_t)(row0 + r) * N + col;
        float v = acc[mi][ni][r] + bc;
        if (MODE == 0) {
          v += ((const float*)residv)[idx];
          ((bf16*)outv)[idx] = (bf16)v;
        } else {
          v += (float)((const bf16*)residv)[idx];
          ((float*)outv)[idx] = v;
        }
      }
    }
  }
}

// ========== Flash attention (causal), swapped-QK, static-max softmax ==========
// Q pre-scaled by 0.125*log2e in the QKV epilogue -> exp2f(s) directly.
// 256 thr (4 waves x 32 q), grid (16,32), cross-block pairing remap.
__global__ __launch_bounds__(256) void attn_kernel(const bf16* __restrict__ qkv,
                                                   const bf16* __restrict__ vt,
                                                   bf16* __restrict__ attn_out) {
  __shared__ bf16 Ks[3][4096];
  __shared__ bf16 Vs[3][4096];
  const int t = threadIdx.x, lane = t & 63, w = t >> 6;
  const int l31 = lane & 31, lh = lane >> 5;
  const int bx = blockIdx.x, by = blockIdx.y;
  const int b = by >> 4, h = by & 15;
  const int g = (bx + by) & 15;
  const int qb = (by < 16) ? g : 15 - g;  // CU-pair trip counts sum to const
  const int qw = qb * 128 + w * 32;
  const int qq = qw + l31;
  const int nt = 2 * qb + 2;

  bf16x8 qf[4];
  {
    const bf16* qp = qkv + (size_t)(b * 2048 + qq) * 3072 + h * 64 + lh * 8;
#pragma unroll
    for (int c = 0; c < 4; ++c) qf[c] = *(const bf16x8*)(qp + c * 16);
  }

  const int r0 = t >> 3, c16 = t & 7;
  const int swsl = 8 * (c16 ^ (r0 & 7));
  const bf16* kp0 = qkv + (size_t)(b * 2048 + r0) * 3072 + 1024 + h * 64 + swsl;
  const bf16* kp1 = qkv + (size_t)(b * 2048 + r0 + 32) * 3072 + 1024 + h * 64 + swsl;
  const bf16* vp0 = vt + ((size_t)by * 64 + r0) * 2048 + swsl;
  const bf16* vp1 = vp0 + (size_t)32 * 2048;

#define ASTAGE(buf)                          \
  do {                                       \
    gll16(kp0, &Ks[buf][t * 8]);             \
    gll16(kp1, &Ks[buf][2048 + t * 8]);      \
    gll16(vp0, &Vs[buf][t * 8]);             \
    gll16(vp1, &Vs[buf][2048 + t * 8]);      \
    kp0 += (size_t)64 * 3072;                \
    kp1 += (size_t)64 * 3072;                \
    vp0 += 64;                               \
    vp1 += 64;                               \
  } while (0)

  const f32x16 z16 = {0.f, 0.f, 0.f, 0.f, 0.f, 0.f, 0.f, 0.f,
                      0.f, 0.f, 0.f, 0.f, 0.f, 0.f, 0.f, 0.f};
  f32x16 o0a = z16, o0b = z16, o1a = z16, o1b = z16;
  float lsum = 0.f;

  ASTAGE(0);
  ASTAGE(1);  // nt >= 2 always
  int b0 = 0, b1 = 1, b2 = 2;
  for (int tt = 0; tt < nt; ++tt) {
    const int kv0 = tt * 64;
    if (tt < nt - 1) asm volatile("s_waitcnt vmcnt(4)" ::: "memory");
    else             asm volatile("s_waitcnt vmcnt(0)" ::: "memory");
    __builtin_amdgcn_s_barrier();
    if (tt + 2 < nt) ASTAGE(b2);
    if (kv0 <= qw + 31) {
      const bf16* kbp = Ks[b0];
      const bf16* vbp = Vs[b0];
      const bool up = (kv0 + 32) <= (qw + 31);
      f32x16 s0v = z16, s1v = z16;
      __builtin_amdgcn_s_setprio(1);
#pragma unroll
      for (int c = 0; c < 4; ++c) {
        const int slot = ((c * 2 + lh) ^ (l31 & 7)) * 16;
        const bf16x8 a0 = *(const bf16x8*)((const char*)kbp + l31 * 128 + slot);
        s0v = MFMA32(a0, qf[c], s0v);
      }
      if (up) {
#pragma unroll
        for (int c = 0; c < 4; ++c) {
          const int slot = ((c * 2 + lh) ^ (l31 & 7)) * 16;
          const bf16x8 a1 = *(const bf16x8*)((const char*)kbp + (32 + l31) * 128 + slot);
          s1v = MFMA32(a1, qf[c], s1v);
        }
      }
      __builtin_amdgcn_s_setprio(0);
      if (kv0 + 64 > qw) {
#pragma unroll
        for (int j = 0; j < 16; ++j) {
          const int kr = kv0 + (j & 3) + 8 * (j >> 2) + 4 * lh;
          if (kr > qq) s0v[j] = -1e30f;
          if (kr + 32 > qq) s1v[j] = -1e30f;
        }
      }
#pragma unroll
      for (int j = 0; j < 16; ++j) {
        s0v[j] = exp2f(s0v[j]);
        lsum += s0v[j];
      }
      if (up) {
#pragma unroll
        for (int j = 0; j < 16; ++j) {
          s1v[j] = exp2f(s1v[j]);
          lsum += s1v[j];
        }
      }
      unsigned int w0[8];
#pragma unroll
      for (int j = 0; j < 8; ++j) w0[j] = (unsigned int)cvtpk(s0v[2 * j], s0v[2 * j + 1]);
#define PVHALF2(WW, KB, OA, OB)                                                      \
  do {                                                                               \
    const uint2v e0 = __builtin_amdgcn_permlane32_swap(WW[0], WW[2], false, false);  \
    const uint2v e1 = __builtin_amdgcn_permlane32_swap(WW[1], WW[3], false, false);  \
    const uint2v e2 = __builtin_amdgcn_permlane32_swap(WW[4], WW[6], false, false);  \
    const uint2v e3 = __builtin_amdgcn_permlane32_swap(WW[5], WW[7], false, false);  \
    union { unsigned int i[4]; bf16x8 v; } pA, pB;                                   \
    pA.i[0] = e0[0]; pA.i[1] = e1[0]; pA.i[2] = e0[1]; pA.i[3] = e1[1];              \
    pB.i[0] = e2[0]; pB.i[1] = e3[0]; pB.i[2] = e2[1]; pB.i[3] = e3[1];              \
    const int sA = (((KB)*4 + lh) ^ (l31 & 7)) * 16;                                 \
    const int sB = (((KB)*4 + 2 + lh) ^ (l31 & 7)) * 16;                             \
    const bf16x8 vA0 = *(const bf16x8*)((const char*)vbp + l31 * 128 + sA);          \
    const bf16x8 vA1 = *(const bf16x8*)((const char*)vbp + (32 + l31) * 128 + sA);   \
    const bf16x8 vB0 = *(const bf16x8*)((const char*)vbp + l31 * 128 + sB);          \
    const bf16x8 vB1 = *(const bf16x8*)((const char*)vbp + (32 + l31) * 128 + sB);   \
    OA = MFMA32(vA0, pA.v, OA);                                                      \
    OB = MFMA32(vA1, pA.v, OB);                                                      \
    OA = MFMA32(vB0, pB.v, OA);                                                      \
    OB = MFMA32(vB1, pB.v, OB);                                                      \
  } while (0)
      __builtin_amdgcn_s_setprio(1);
      PVHALF2(w0, 0, o0a, o1a);
      __builtin_amdgcn_s_setprio(0);
      if (up) {
        unsigned int w1[8];
#pragma unroll
        for (int j = 0; j < 8; ++j) w1[j] = (unsigned int)cvtpk(s1v[2 * j], s1v[2 * j + 1]);
        __builtin_amdgcn_s_setprio(1);
        PVHALF2(w1, 1, o0b, o1b);
        __builtin_amdgcn_s_setprio(0);
      }
#undef PVHALF2
    }
    const int tmp = b0; b0 = b1; b1 = b2; b2 = tmp;
  }
#undef ASTAGE

  lsum += __shfl_xor(lsum, 32);
  const float rinv = 1.f / lsum;
  const f32x16 oacc0 = o0a + o0b, oacc1 = o1a + o1b;
  bf16* op = attn_out + (size_t)(b * 2048 + qq) * 1024 + h * 64;
#pragma unroll
  for (int gR = 0; gR < 4; ++gR) {
    bf16x4 o0, o1;
#pragma unroll
    for (int r = 0; r < 4; ++r) {
      o0[r] = (bf16)(oacc0[4 * gR + r] * rinv);
      o1[r] = (bf16)(oacc1[4 * gR + r] * rinv);
    }
    *(bf16x4*)(op + 8 * gR + 4 * lh) = o0;
    *(bf16x4*)(op + 32 + 8 * gR + 4 * lh) = o1;
  }
}

// ---------------- launch ----------------
extern "C" void kernel_launch(void* const* d_in, const int* in_sizes, int n_in,
                              void* d_out, int out_size, void* d_ws, size_t ws_size,
                              hipStream_t stream) {
  (void)in_sizes; (void)n_in; (void)out_size; (void)ws_size;
  const float* hidden = (const float*)d_in[0];
  const float* qkv_w  = (const float*)d_in[1];
  const float* qkv_b  = (const float*)d_in[2];
  const float* out_w  = (const float*)d_in[3];
  const float* out_b  = (const float*)d_in[4];
  const float* fc1_w  = (const float*)d_in[5];
  const float* fc1_b  = (const float*)d_in[6];
  const float* fc2_w  = (const float*)d_in[7];
  const float* fc2_b  = (const float*)d_in[8];
  const float* ln1_g  = (const float*)d_in[9];
  const float* ln1_b  = (const float*)d_in[10];
  const float* ln2_g  = (const float*)d_in[11];
  const float* ln2_b  = (const float*)d_in[12];
  float* outp = (float*)d_out;

  char* ws = (char*)d_ws;
  bf16*  ln1o  = (bf16*)(ws);
  bf16*  qkvb  = (bf16*)(ws + ((size_t)8 << 20));
  bf16*  vtb   = (bf16*)(ws + ((size_t)32 << 20));
  bf16*  atto  = (bf16*)(ws + ((size_t)40 << 20));
  bf16*  res1b = (bf16*)(ws + ((size_t)48 << 20));
  bf16*  ln2o  = (bf16*)(ws + ((size_t)64 << 20));
  bf16*  ff1   = (bf16*)(ws + ((size_t)72 << 20));
  bf16*  wqkv  = (bf16*)(ws + ((size_t)104 << 20));
  bf16*  wout  = (bf16*)(ws + ((size_t)110 << 20));
  bf16*  wfc1  = (bf16*)(ws + ((size_t)112 << 20));
  bf16*  wfc2  = (bf16*)(ws + ((size_t)120 << 20));

  prep_kernel<<<16384, 256, 0, stream>>>(qkv_w, wqkv, out_w, wout, fc1_w, wfc1, fc2_w, wfc2,
                                         hidden, ln1_g, ln1_b, ln1o);
  gemm256<0><<<192, 512, 0, stream>>>(ln1o, wqkv, qkv_b, qkvb, vtb, 3072, 1024, 12);
  attn_kernel<<<dim3(16, 32), 256, 0, stream>>>(qkvb, vtb, atto);
  gemm64<0><<<512, 256, 0, stream>>>(atto, wout, out_b, hidden, res1b, 1024, 1024, 8);
  ln_kernel<<<4096, 256, 0, stream>>>(res1b, ln2_g, ln2_b, ln2o);
  gemm256<1><<<256, 512, 0, stream>>>(ln2o, wfc1, fc1_b, ff1, nullptr, 4096, 1024, 16);
  gemm64<1><<<512, 256, 0, stream>>>(ff1, wfc2, fc2_b, res1b, outp, 1024, 4096, 8);
}